// Round 11
// baseline (220.999 us; speedup 1.0000x reference)
//
#include <hip/hip_runtime.h>
#include <hip/hip_bf16.h>

#define N_NODES 50000
#define N_EDGES 600000
#define D_IN 256
#define D 128

#define GEMM_BLOCKS ((N_NODES + 31) / 32)    // 1563
#define EDGE_BLOCKS ((N_EDGES + 255) / 256)  // 2344
#define MIX_BLOCKS 3910                      // 782 groups x 5 (2 gemm + 3 fill)
#define OUT_CHUNKS (N_NODES / 16)            // 3125
#define BCAP 32                              // bucket capacity per node
#define OVF_CAP 2048                         // overflow entries (P(use)~1e-7)

typedef unsigned short ushort_t;
typedef __attribute__((ext_vector_type(8))) short bf16x8;
typedef __attribute__((ext_vector_type(16))) float f32x16;

__device__ __forceinline__ float bf2f(ushort_t u) {
  union { unsigned int i; float f; } v;
  v.i = ((unsigned int)u) << 16;
  return v.f;
}
__device__ __forceinline__ ushort_t f2bf(float f) {
  union { float f; unsigned int i; } v;
  v.f = f;
  unsigned int x = v.i;
  unsigned int r = (x + 0x7FFFu + ((x >> 16) & 1u)) >> 16;  // RNE
  return (ushort_t)r;
}
__device__ __forceinline__ float bflo(unsigned int u) {
  union { unsigned int i; float f; } v;
  v.i = u << 16;
  return v.f;
}
__device__ __forceinline__ float bfhi(unsigned int u) {
  union { unsigned int i; float f; } v;
  v.i = u & 0xFFFF0000u;
  return v.f;
}

// Swizzled-W addressing: element (j,k) of [128,KDIM] W, hi/lo split:
//   wv=j>>5, fm=j&31, kh=k>>7, t=(k>>4)&7, fq=(k>>3)&1, c=k&7, lane=fq*32+fm
//   addr = (((wv*(KDIM/128)+kh)*8 + t)*2 + hl)*512 + lane*8 + c   [ushorts]

// ---------------- k1: weight prep only (no edge work) ----------------
__global__ __launch_bounds__(256) void k_wprep(
    const float* __restrict__ wn, const float* __restrict__ w1,
    const float* __restrict__ bn, const float* __restrict__ w2,
    const float* __restrict__ b1, const float* __restrict__ b2,
    ushort_t* __restrict__ WcSw, ushort_t* __restrict__ W2Sw,
    float* __restrict__ bias_ws,
    ushort_t* __restrict__ T1z, ushort_t* __restrict__ T2z) {
  int bid = blockIdx.x;
  int tid = threadIdx.x;
  float* bcf = bias_ws;
  float* b1f = bias_ws + 128;
  float* b2f = bias_ws + 256;
  if (bid < 128) {
    int j = bid;
    int k = tid;
    float acc = 0.f;
#pragma unroll 8
    for (int m = 0; m < 128; m++)
      acc += w1[j * 128 + m] * wn[m * 256 + k];
    ushort_t h = f2bf(acc);
    ushort_t l = f2bf(acc - bf2f(h));
    int wv = j >> 5, fm = j & 31;
    int kh = k >> 7, t = (k >> 4) & 7, fq = (k >> 3) & 1, c = k & 7;
    int lane = fq * 32 + fm;
    int base = ((wv * 2 + kh) * 8 + t) * 2 * 512 + lane * 8 + c;  // KH=2
    WcSw[base] = h;
    WcSw[base + 512] = l;
    if (k == 0) {
      float s = 0.f;
      for (int m = 0; m < 128; m++) s += w1[j * 128 + m] * bn[m];
      bcf[j] = s;
    }
  } else if (bid < 193) {
    int i = (bid - 128) * 256 + tid;
    if (i < 16384) {
      float v = w2[i];
      ushort_t h = f2bf(v);
      ushort_t l = f2bf(v - bf2f(h));
      int j = i >> 7, k = i & 127;
      int wv = j >> 5, fm = j & 31;
      int t = (k >> 4) & 7, fq = (k >> 3) & 1, c = k & 7;
      int lane = fq * 32 + fm;
      int base = (wv * 8 + t) * 2 * 512 + lane * 8 + c;  // KH=1
      W2Sw[base] = h;
      W2Sw[base + 512] = l;
    } else if (i < 16512) {
      b1f[i - 16384] = b1[i - 16384];
    } else if (i < 16640) {
      b2f[i - 16512] = b2[i - 16512];
    }
  } else {
    // zero the shared dummy row T[N_NODES] (gather padding target)
    unsigned int* z1 = (unsigned int*)&T1z[(size_t)N_NODES * D];
    unsigned int* z2 = (unsigned int*)&T2z[(size_t)N_NODES * D];
    if (tid < 64) z1[tid] = 0u;
    else if (tid < 128) z2[tid - 64] = 0u;
  }
}

// ---------------- k2: conv1-GEMM (UNSCALED T1) || edge fill ----------------
// T1 has no dinv dependency -> edge fill (deg atomic + ushort bucket) runs
// CONCURRENTLY in the same dispatch, interleaved 2:3.
__global__ __launch_bounds__(256) void k_gemm_fill(
    const float* __restrict__ Xv, const int* __restrict__ tokens,
    const ushort_t* __restrict__ Wsw, const float* __restrict__ bias,
    ushort_t* __restrict__ OutT,
    const int* __restrict__ src, const int* __restrict__ dst,
    int* __restrict__ deg, ushort_t* __restrict__ bucket,
    int* __restrict__ ovfc, int* __restrict__ ovf) {
  constexpr int XS = 136;
  __shared__ __align__(16) ushort_t xh_lds[32 * XS];
  __shared__ __align__(16) ushort_t xl_lds[32 * XS];

  int bid = blockIdx.x;
  int tid = threadIdx.x;
  int grp = bid / 5, r = bid % 5;
  if (r >= 2) {
    // ---- fill path: deg atomic gives the slot; ushort bucket row = 64B ----
    int c = grp * 3 + (r - 2);
    if (c >= EDGE_BLOCKS) return;
    int e = c * 256 + tid;
    if (e < N_EDGES) {
      int d = dst[e];
      int s = src[e];
      int pos = atomicAdd(&deg[d], 1);
      if (pos < BCAP) {
        bucket[d * BCAP + pos] = (ushort_t)s;
      } else {
        int oi = atomicAdd(ovfc, 1);
        if (oi < OVF_CAP) {
          ovf[2 * oi] = d;
          ovf[2 * oi + 1] = s;
        }
      }
    }
    return;
  }

  // ---- GEMM path ----
  int t = grp * 2 + r;
  if (t >= GEMM_BLOCKS) return;
  int lane = tid & 63;
  int wv = tid >> 6;
  int node0 = t * 32;
  int fm = lane & 31;
  int fq = lane >> 5;
  int r8 = tid >> 5;   // 0..7
  int c32 = tid & 31;  // 0..31

  const char* xb = (const char*)Xv;
  float4 v0[4], v1[4];
  int rows[4];
#pragma unroll
  for (int i = 0; i < 4; i++) {
    rows[i] = r8 * 4 + i;
    int tk = tokens[min(node0 + rows[i], N_NODES - 1)];
    unsigned off = (unsigned)tk * (D_IN * 4) + (unsigned)c32 * 16;
    v0[i] = *(const float4*)(xb + off);
    v1[i] = *(const float4*)(xb + off + 512);
  }

  f32x16 acc;
#pragma unroll
  for (int q = 0; q < 16; q++) acc[q] = 0.f;

#pragma unroll
  for (int kh = 0; kh < 2; kh++) {
#pragma unroll
    for (int i = 0; i < 4; i++) {
      float4 v = (kh == 0) ? v0[i] : v1[i];
      ushort4 h, l;
      h.x = f2bf(v.x); l.x = f2bf(v.x - bf2f(h.x));
      h.y = f2bf(v.y); l.y = f2bf(v.y - bf2f(h.y));
      h.z = f2bf(v.z); l.z = f2bf(v.z - bf2f(h.z));
      h.w = f2bf(v.w); l.w = f2bf(v.w - bf2f(h.w));
      *(ushort4*)&xh_lds[rows[i] * XS + 4 * c32] = h;
      *(ushort4*)&xl_lds[rows[i] * XS + 4 * c32] = l;
    }
    __syncthreads();

    const ushort_t* wb = Wsw + ((size_t)(wv * 2 + kh) * 8) * 2 * 512 + lane * 8;
#pragma unroll
    for (int tc = 0; tc < 2; tc++) {
      bf16x8 wbh[4], wbl[4];
#pragma unroll
      for (int t4 = 0; t4 < 4; t4++) {
        wbh[t4] = *(const bf16x8*)(wb + (size_t)(tc * 4 + t4) * 1024);
        wbl[t4] = *(const bf16x8*)(wb + (size_t)(tc * 4 + t4) * 1024 + 512);
      }
#pragma unroll
      for (int t4 = 0; t4 < 4; t4++) {
        int ko = (tc * 4 + t4) * 16 + fq * 8;
        bf16x8 ah = *(const bf16x8*)&xh_lds[fm * XS + ko];
        bf16x8 al = *(const bf16x8*)&xl_lds[fm * XS + ko];
        acc = __builtin_amdgcn_mfma_f32_32x32x16_bf16(ah, wbh[t4], acc, 0, 0, 0);
        acc = __builtin_amdgcn_mfma_f32_32x32x16_bf16(ah, wbl[t4], acc, 0, 0, 0);
        acc = __builtin_amdgcn_mfma_f32_32x32x16_bf16(al, wbh[t4], acc, 0, 0, 0);
      }
    }
    if (kh == 0) __syncthreads();  // all reads done before buffer reuse
  }

  int j = wv * 32 + fm;
  float bv = bias[j];
#pragma unroll
  for (int q = 0; q < 16; q++) {
    int row = (q & 3) + 8 * (q >> 2) + 4 * fq;
    int node = node0 + row;
    if (node < N_NODES)
      OutT[(size_t)node * D + j] = f2bf(acc[q] + bv);  // UNSCALED
  }
}

// ---------------- gather primitives ----------------
__device__ __forceinline__ void fma8(float acc[8], uint4 u, float f) {
  acc[0] = fmaf(bflo(u.x), f, acc[0]);
  acc[1] = fmaf(bfhi(u.x), f, acc[1]);
  acc[2] = fmaf(bflo(u.y), f, acc[2]);
  acc[3] = fmaf(bfhi(u.y), f, acc[3]);
  acc[4] = fmaf(bflo(u.z), f, acc[4]);
  acc[5] = fmaf(bfhi(u.z), f, acc[5]);
  acc[6] = fmaf(bflo(u.w), f, acc[6]);
  acc[7] = fmaf(bfhi(u.w), f, acc[7]);
}
__device__ __forceinline__ void addu4(float acc[8], uint4 u) {
  acc[0] += bflo(u.x);
  acc[1] += bfhi(u.x);
  acc[2] += bflo(u.y);
  acc[3] += bfhi(u.y);
  acc[4] += bflo(u.z);
  acc[5] += bfhi(u.z);
  acc[6] += bflo(u.w);
  acc[7] += bfhi(u.w);
}

__device__ __forceinline__ uint4 ldrow(const char* tbase, int s, int h) {
  return *(const uint4*)(tbase + (((unsigned)s << 8) + ((unsigned)h << 4)));
}

// scaled burst: per-row scale f fetched by shfl in the CONSUME loop
// (no f[8] array -> -8 VGPR vs round 10).
__device__ __forceinline__ void burst8s(const char* tbase, int sidx, float scl,
                                        int gbase, int qoff, int h, float acc[8]) {
  uint4 u[8];
#pragma unroll
  for (int q = 0; q < 8; q++) {
    int s = __shfl(sidx, gbase + qoff + q);
    u[q] = ldrow(tbase, s, h);
  }
#pragma unroll
  for (int q = 0; q < 8; q++)
    fma8(acc, u[q], __shfl(scl, gbase + qoff + q));
}

// plain burst: no scaling (rows pre-scaled by producer).
__device__ __forceinline__ void burst8p(const char* tbase, int sidx,
                                        int gbase, int qoff, int h, float acc[8]) {
  uint4 u[8];
#pragma unroll
  for (int q = 0; q < 8; q++) {
    int s = __shfl(sidx, gbase + qoff + q);
    u[q] = ldrow(tbase, s, h);
  }
#pragma unroll
  for (int q = 0; q < 8; q++) addu4(acc, u[q]);
}

// k3 gather: rows UNSCALED, scale by dinv[s]=rsqrt(deg[s]+1) per row.
__device__ __forceinline__ void gather_scaled(
    const char* tbase, const ushort_t* __restrict__ bucket,
    const int* __restrict__ deg, const int* __restrict__ ovf, int novf,
    int node, int degv, bool valid, int gbase, int h, float acc[8]) {
  int cnt = valid ? min(degv, BCAP) : 0;
  int sidx = (h < cnt) ? (int)bucket[node * BCAP + h] : N_NODES;
  float scl = rsqrtf((float)(deg[sidx] + 1));  // deg[N_NODES]=0 -> 1.0, row=0
  burst8s(tbase, sidx, scl, gbase, 0, h, acc);
  burst8s(tbase, sidx, scl, gbase, 8, h, acc);
  for (int b2 = 16; b2 < cnt; b2 += 16) {  // deg in (16,32]: one more batch
    int sx = (b2 + h < cnt) ? (int)bucket[node * BCAP + b2 + h] : N_NODES;
    float sc = rsqrtf((float)(deg[sx] + 1));
    burst8s(tbase, sx, sc, gbase, 0, h, acc);
    burst8s(tbase, sx, sc, gbase, 8, h, acc);
  }
  if (valid && degv > BCAP) {  // exact overflow handling (P~1e-7)
    for (int i = 0; i < novf; i++) {
      if (ovf[2 * i] == node) {
        int s = ovf[2 * i + 1];
        fma8(acc, ldrow(tbase, s, h), rsqrtf((float)(deg[s] + 1)));
      }
    }
  }
}

// k4 gather: rows PRE-SCALED by producer -> plain adds, no deg loads.
__device__ __forceinline__ void gather_plain(
    const char* tbase, const ushort_t* __restrict__ bucket,
    const int* __restrict__ ovf, int novf,
    int node, int degv, bool valid, int gbase, int h, float acc[8]) {
  int cnt = valid ? min(degv, BCAP) : 0;
  int sidx = (h < cnt) ? (int)bucket[node * BCAP + h] : N_NODES;
  burst8p(tbase, sidx, gbase, 0, h, acc);
  burst8p(tbase, sidx, gbase, 8, h, acc);
  for (int b2 = 16; b2 < cnt; b2 += 16) {
    int sx = (b2 + h < cnt) ? (int)bucket[node * BCAP + b2 + h] : N_NODES;
    burst8p(tbase, sx, gbase, 0, h, acc);
    burst8p(tbase, sx, gbase, 8, h, acc);
  }
  if (valid && degv > BCAP) {
    for (int i = 0; i < novf; i++) {
      if (ovf[2 * i] == node) addu4(acc, ldrow(tbase, ovf[2 * i + 1], h));
    }
  }
}

// epilogue: bias+relu+hi/lo pack -> LDS
__device__ __forceinline__ void epi_lds(
    const float acc[8], bool vv, float di, float4 bA, float4 bB,
    int row, int h, ushort_t* xh_lds, ushort_t* xl_lds) {
  constexpr int XS = 136;
  bf16x8 ph, pl;
  if (vv) {
    float val[8];
    val[0] = fmaxf(di * acc[0] + bA.x, 0.f);
    val[1] = fmaxf(di * acc[1] + bA.y, 0.f);
    val[2] = fmaxf(di * acc[2] + bA.z, 0.f);
    val[3] = fmaxf(di * acc[3] + bA.w, 0.f);
    val[4] = fmaxf(di * acc[4] + bB.x, 0.f);
    val[5] = fmaxf(di * acc[5] + bB.y, 0.f);
    val[6] = fmaxf(di * acc[6] + bB.z, 0.f);
    val[7] = fmaxf(di * acc[7] + bB.w, 0.f);
#pragma unroll
    for (int q = 0; q < 8; q++) {
      ushort_t hq = f2bf(val[q]);
      ph[q] = (short)hq;
      pl[q] = (short)f2bf(val[q] - bf2f(hq));
    }
  } else {
#pragma unroll
    for (int q = 0; q < 8; q++) { ph[q] = 0; pl[q] = 0; }
  }
  *(bf16x8*)&xh_lds[row * XS + h * 8] = ph;
  *(bf16x8*)&xl_lds[row * XS + h * 8] = pl;
}

// ---------------- k3: FUSED aggregate1 + conv2-GEMM ----------------
// Gathers UNSCALED T1 with per-row dinv; writes T2 PRE-SCALED by dinv[node]
// (deg is final here; epilogue deg loads are coalesced) -> k4 gather is
// scale-free. Pass A's epilogue runs BEFORE gather B so one acc[] is reused
// (lower peak VGPR; LDS is not read until after the sync).
__global__ __launch_bounds__(256) void k_agg_gemm(
    const ushort_t* __restrict__ t1, const int* __restrict__ deg,
    const ushort_t* __restrict__ bucket, const int* __restrict__ ovfc,
    const int* __restrict__ ovf, const float* __restrict__ b1f,
    const ushort_t* __restrict__ Wsw, ushort_t* __restrict__ OutT2) {
  constexpr int XS = 136;
  __shared__ __align__(16) ushort_t xh_lds[32 * XS];
  __shared__ __align__(16) ushort_t xl_lds[32 * XS];

  int tid = threadIdx.x;
  int lane = tid & 63;
  int wv = tid >> 6;
  int node0 = blockIdx.x * 32;
  int fm = lane & 31;
  int fq = lane >> 5;
  int g = lane >> 4;   // group 0..3
  int h = lane & 15;   // dim-chunk 0..15
  int gbase = lane & 48;

  const char* tb = (const char*)t1;
  float4 bA = *(const float4*)&b1f[h * 8];
  float4 bB = *(const float4*)&b1f[h * 8 + 4];
  int novf = *ovfc;

  // hoisted per-wave deg loads (8 nodes)
  int node0w = node0 + wv * 8;
  int dgl = deg[min(node0w + min(lane, 7), N_NODES - 1)];

  // ---- pass A (wave rows 0..3) ----
  {
    int nodeA = node0w + g;
    int degA = __shfl(dgl, g);
    bool vA = nodeA < N_NODES;
    float diA = rsqrtf((float)(degA + 1));
    float acc[8];
#pragma unroll
    for (int q = 0; q < 8; q++) acc[q] = 0.f;
    fma8(acc, ldrow(tb, vA ? nodeA : N_NODES, h), diA);  // self * own dinv
    gather_scaled(tb, bucket, deg, ovf, novf, nodeA, degA, vA, gbase, h, acc);
    epi_lds(acc, vA, diA, bA, bB, wv * 8 + g, h, xh_lds, xl_lds);
  }
  // ---- pass B (wave rows 4..7) ----
  {
    int nodeB = node0w + 4 + g;
    int degB = __shfl(dgl, 4 + g);
    bool vB = nodeB < N_NODES;
    float diB = rsqrtf((float)(degB + 1));
    float acc[8];
#pragma unroll
    for (int q = 0; q < 8; q++) acc[q] = 0.f;
    fma8(acc, ldrow(tb, vB ? nodeB : N_NODES, h), diB);
    gather_scaled(tb, bucket, deg, ovf, novf, nodeB, degB, vB, gbase, h, acc);
    epi_lds(acc, vB, diB, bA, bB, wv * 8 + 4 + g, h, xh_lds, xl_lds);
  }
  __syncthreads();

  f32x16 acc;
#pragma unroll
  for (int q = 0; q < 16; q++) acc[q] = 0.f;
  {
    const ushort_t* wb = Wsw + ((size_t)wv * 8) * 2 * 512 + lane * 8;
#pragma unroll
    for (int tc = 0; tc < 2; tc++) {
      bf16x8 wbh[4], wbl[4];
#pragma unroll
      for (int t4 = 0; t4 < 4; t4++) {
        wbh[t4] = *(const bf16x8*)(wb + (size_t)(tc * 4 + t4) * 1024);
        wbl[t4] = *(const bf16x8*)(wb + (size_t)(tc * 4 + t4) * 1024 + 512);
      }
#pragma unroll
      for (int t4 = 0; t4 < 4; t4++) {
        int ko = (tc * 4 + t4) * 16 + fq * 8;
        bf16x8 ah = *(const bf16x8*)&xh_lds[fm * XS + ko];
        bf16x8 al = *(const bf16x8*)&xl_lds[fm * XS + ko];
        acc = __builtin_amdgcn_mfma_f32_32x32x16_bf16(ah, wbh[t4], acc, 0, 0, 0);
        acc = __builtin_amdgcn_mfma_f32_32x32x16_bf16(ah, wbl[t4], acc, 0, 0, 0);
        acc = __builtin_amdgcn_mfma_f32_32x32x16_bf16(al, wbh[t4], acc, 0, 0, 0);
      }
    }
  }
  int j = wv * 32 + fm;
#pragma unroll
  for (int q = 0; q < 16; q++) {
    int row = (q & 3) + 8 * (q >> 2) + 4 * fq;
    int node = node0 + row;
    if (node < N_NODES) {
      float di = rsqrtf((float)(deg[node] + 1));  // coalesced: contiguous nodes
      OutT2[(size_t)node * D + j] = f2bf(acc[q] * di);  // PRE-SCALED T2
    }
  }
}

// ---------------- k4: final aggregation -> fp32 out ----------------
// T2 rows are pre-scaled -> plain-add gather (no random deg loads).
__global__ __launch_bounds__(256) void k_agg_out(
    const ushort_t* __restrict__ t, const int* __restrict__ deg,
    const ushort_t* __restrict__ bucket, const int* __restrict__ ovfc,
    const int* __restrict__ ovf, const float* __restrict__ bias,
    float* __restrict__ out_f) {
  int wv = threadIdx.x >> 6;
  int lane = threadIdx.x & 63;
  int g = lane >> 4;
  int h = lane & 15;
  int gbase = lane & 48;
  int nodew = blockIdx.x * 16 + wv * 4;
  int dgl = deg[min(nodew + min(lane, 3), N_NODES - 1)];
  int node = nodew + g;
  int degn = __shfl(dgl, g);
  bool vn = node < N_NODES;
  float di = rsqrtf((float)(degn + 1));
  int novf = *ovfc;

  const char* tb = (const char*)t;
  float acc[8];
#pragma unroll
  for (int q = 0; q < 8; q++) acc[q] = 0.f;
  addu4(acc, ldrow(tb, vn ? node : N_NODES, h));  // self (already dinv-scaled)
  gather_plain(tb, bucket, ovf, novf, node, degn, vn, gbase, h, acc);

  if (!vn) return;
  float4 bA = *(const float4*)&bias[h * 8];
  float4 bB = *(const float4*)&bias[h * 8 + 4];
  float4 o0, o1;
  o0.x = di * acc[0] + bA.x;
  o0.y = di * acc[1] + bA.y;
  o0.z = di * acc[2] + bA.z;
  o0.w = di * acc[3] + bA.w;
  o1.x = di * acc[4] + bB.x;
  o1.y = di * acc[5] + bB.y;
  o1.z = di * acc[6] + bB.z;
  o1.w = di * acc[7] + bB.w;
  *(float4*)&out_f[(size_t)node * D + h * 8] = o0;
  *(float4*)&out_f[(size_t)node * D + h * 8 + 4] = o1;
}

extern "C" void kernel_launch(void* const* d_in, const int* in_sizes, int n_in,
                              void* d_out, int out_size, void* d_ws, size_t ws_size,
                              hipStream_t stream) {
  const int* tokens = (const int*)d_in[0];
  const int* edge = (const int*)d_in[1];  // [2][E]
  const float* embed = (const float*)d_in[2];
  const float* Wn = (const float*)d_in[3];
  const float* bn = (const float*)d_in[4];
  const float* w1 = (const float*)d_in[5];
  const float* b1 = (const float*)d_in[6];
  const float* w2 = (const float*)d_in[7];
  const float* b2 = (const float*)d_in[8];
  float* out = (float*)d_out;  // fp32 output

  const int* src = edge;
  const int* dst = edge + N_EDGES;

  char* ws = (char*)d_ws;
  // T1/T2 have one extra ZERO row at index N_NODES (gather padding target)
  ushort_t* T1 = (ushort_t*)ws;                  // 12,800,256 B
  ushort_t* T2 = (ushort_t*)(ws + 12800256);     // 12,800,256 B
  ushort_t* bucket = (ushort_t*)(ws + 25600512); // 3,200,000 B (50K x 32 u16)
  int* deg = (int*)(ws + 28800512);              // 200,064 B (50001 ints, pad)
  int* ovfc = (int*)(ws + 29000576);             // 128 B (isolated counter)
  int* ovf = (int*)(ws + 29000704);              // 16,384 B (2048 pairs)
  ushort_t* WcSw = (ushort_t*)(ws + 29017088);   // 131,072 B (swizzled hi/lo)
  ushort_t* W2Sw = (ushort_t*)(ws + 29148160);   // 65,536 B (swizzled hi/lo)
  float* bias_ws = (float*)(ws + 29213696);      // bc | b1 | b2 (1,536 B)
  float* bcf = bias_ws;
  float* b1f = bias_ws + 128;
  float* b2f = bias_ws + 256;

  // zero deg (incl. deg[N_NODES]=0 for dummy-row scale) + overflow counter
  hipMemsetAsync(deg, 0, 200192, stream);

  // --- k1: weight prep only (small, fast) ---
  k_wprep<<<194, 256, 0, stream>>>(
      Wn, w1, bn, w2, b1, b2, WcSw, W2Sw, bias_ws, T1, T2);

  // --- k2: conv1 T1 = gather(e)@Wc^T + bc (UNSCALED) || edge fill ---
  k_gemm_fill<<<MIX_BLOCKS, 256, 0, stream>>>(
      embed, tokens, WcSw, bcf, T1, src, dst, deg, bucket, ovfc, ovf);

  // --- k3: x1 = relu(dinv*agg_scaled(T1)+b1); T2 = dinv*(x1@w2^T) ---
  k_agg_gemm<<<GEMM_BLOCKS, 256, 0, stream>>>(
      T1, deg, bucket, ovfc, ovf, b1f, W2Sw, T2);

  // --- k4: out = dinv*agg_plain(T2) + b2 (fp32) ---
  k_agg_out<<<OUT_CHUNKS, 256, 0, stream>>>(
      T2, deg, bucket, ovfc, ovf, b2f, out);
}

// Round 12
// 218.417 us; speedup vs baseline: 1.0118x; 1.0118x over previous
//
#include <hip/hip_runtime.h>
#include <hip/hip_bf16.h>

#define N_NODES 50000
#define N_EDGES 600000
#define D_IN 256
#define D 128

#define GEMM_BLOCKS ((N_NODES + 31) / 32)    // 1563
#define EDGE_BLOCKS ((N_EDGES + 255) / 256)  // 2344
#define MIX_BLOCKS 3910                      // 782 groups x 5 (2 gemm + 3 fill)
#define OUT_CHUNKS (N_NODES / 16)            // 3125
#define BCAP 32                              // bucket capacity per node
#define OVF_CAP 2048                         // overflow entries (P(use)~1e-7)

typedef unsigned short ushort_t;
typedef __attribute__((ext_vector_type(8))) short bf16x8;
typedef __attribute__((ext_vector_type(16))) float f32x16;

__device__ __forceinline__ float bf2f(ushort_t u) {
  union { unsigned int i; float f; } v;
  v.i = ((unsigned int)u) << 16;
  return v.f;
}
__device__ __forceinline__ ushort_t f2bf(float f) {
  union { float f; unsigned int i; } v;
  v.f = f;
  unsigned int x = v.i;
  unsigned int r = (x + 0x7FFFu + ((x >> 16) & 1u)) >> 16;  // RNE
  return (ushort_t)r;
}
__device__ __forceinline__ float bflo(unsigned int u) {
  union { unsigned int i; float f; } v;
  v.i = u << 16;
  return v.f;
}
__device__ __forceinline__ float bfhi(unsigned int u) {
  union { unsigned int i; float f; } v;
  v.i = u & 0xFFFF0000u;
  return v.f;
}

// Swizzled-W addressing: element (j,k) of [128,KDIM] W, hi/lo split:
//   wv=j>>5, fm=j&31, kh=k>>7, t=(k>>4)&7, fq=(k>>3)&1, c=k&7, lane=fq*32+fm
//   addr = (((wv*(KDIM/128)+kh)*8 + t)*2 + hl)*512 + lane*8 + c   [ushorts]

// ---------------- k1: weight prep only (no edge work) ----------------
__global__ __launch_bounds__(256) void k_wprep(
    const float* __restrict__ wn, const float* __restrict__ w1,
    const float* __restrict__ bn, const float* __restrict__ w2,
    const float* __restrict__ b1, const float* __restrict__ b2,
    ushort_t* __restrict__ WcSw, ushort_t* __restrict__ W2Sw,
    float* __restrict__ bias_ws,
    ushort_t* __restrict__ T1z, ushort_t* __restrict__ T2z) {
  int bid = blockIdx.x;
  int tid = threadIdx.x;
  float* bcf = bias_ws;
  float* b1f = bias_ws + 128;
  float* b2f = bias_ws + 256;
  if (bid < 128) {
    int j = bid;
    int k = tid;
    float acc = 0.f;
#pragma unroll 8
    for (int m = 0; m < 128; m++)
      acc += w1[j * 128 + m] * wn[m * 256 + k];
    ushort_t h = f2bf(acc);
    ushort_t l = f2bf(acc - bf2f(h));
    int wv = j >> 5, fm = j & 31;
    int kh = k >> 7, t = (k >> 4) & 7, fq = (k >> 3) & 1, c = k & 7;
    int lane = fq * 32 + fm;
    int base = ((wv * 2 + kh) * 8 + t) * 2 * 512 + lane * 8 + c;  // KH=2
    WcSw[base] = h;
    WcSw[base + 512] = l;
    if (k == 0) {
      float s = 0.f;
      for (int m = 0; m < 128; m++) s += w1[j * 128 + m] * bn[m];
      bcf[j] = s;
    }
  } else if (bid < 193) {
    int i = (bid - 128) * 256 + tid;
    if (i < 16384) {
      float v = w2[i];
      ushort_t h = f2bf(v);
      ushort_t l = f2bf(v - bf2f(h));
      int j = i >> 7, k = i & 127;
      int wv = j >> 5, fm = j & 31;
      int t = (k >> 4) & 7, fq = (k >> 3) & 1, c = k & 7;
      int lane = fq * 32 + fm;
      int base = (wv * 8 + t) * 2 * 512 + lane * 8 + c;  // KH=1
      W2Sw[base] = h;
      W2Sw[base + 512] = l;
    } else if (i < 16512) {
      b1f[i - 16384] = b1[i - 16384];
    } else if (i < 16640) {
      b2f[i - 16512] = b2[i - 16512];
    }
  } else {
    // zero the shared dummy row T[N_NODES] (gather padding target)
    unsigned int* z1 = (unsigned int*)&T1z[(size_t)N_NODES * D];
    unsigned int* z2 = (unsigned int*)&T2z[(size_t)N_NODES * D];
    if (tid < 64) z1[tid] = 0u;
    else if (tid < 128) z2[tid - 64] = 0u;
  }
}

// ---------------- k2: conv1-GEMM (UNSCALED T1) || edge fill ----------------
// T1 has no dinv dependency -> edge fill (deg atomic + ushort bucket) runs
// CONCURRENTLY in the same dispatch, interleaved 2:3.
__global__ __launch_bounds__(256) void k_gemm_fill(
    const float* __restrict__ Xv, const int* __restrict__ tokens,
    const ushort_t* __restrict__ Wsw, const float* __restrict__ bias,
    ushort_t* __restrict__ OutT,
    const int* __restrict__ src, const int* __restrict__ dst,
    int* __restrict__ deg, ushort_t* __restrict__ bucket,
    int* __restrict__ ovfc, int* __restrict__ ovf) {
  constexpr int XS = 136;
  __shared__ __align__(16) ushort_t xh_lds[32 * XS];
  __shared__ __align__(16) ushort_t xl_lds[32 * XS];

  int bid = blockIdx.x;
  int tid = threadIdx.x;
  int grp = bid / 5, r = bid % 5;
  if (r >= 2) {
    // ---- fill path: deg atomic gives the slot; ushort bucket row = 64B ----
    int c = grp * 3 + (r - 2);
    if (c >= EDGE_BLOCKS) return;
    int e = c * 256 + tid;
    if (e < N_EDGES) {
      int d = dst[e];
      int s = src[e];
      int pos = atomicAdd(&deg[d], 1);
      if (pos < BCAP) {
        bucket[d * BCAP + pos] = (ushort_t)s;
      } else {
        int oi = atomicAdd(ovfc, 1);
        if (oi < OVF_CAP) {
          ovf[2 * oi] = d;
          ovf[2 * oi + 1] = s;
        }
      }
    }
    return;
  }

  // ---- GEMM path ----
  int t = grp * 2 + r;
  if (t >= GEMM_BLOCKS) return;
  int lane = tid & 63;
  int wv = tid >> 6;
  int node0 = t * 32;
  int fm = lane & 31;
  int fq = lane >> 5;
  int r8 = tid >> 5;   // 0..7
  int c32 = tid & 31;  // 0..31

  const char* xb = (const char*)Xv;
  float4 v0[4], v1[4];
  int rows[4];
#pragma unroll
  for (int i = 0; i < 4; i++) {
    rows[i] = r8 * 4 + i;
    int tk = tokens[min(node0 + rows[i], N_NODES - 1)];
    unsigned off = (unsigned)tk * (D_IN * 4) + (unsigned)c32 * 16;
    v0[i] = *(const float4*)(xb + off);
    v1[i] = *(const float4*)(xb + off + 512);
  }

  f32x16 acc;
#pragma unroll
  for (int q = 0; q < 16; q++) acc[q] = 0.f;

#pragma unroll
  for (int kh = 0; kh < 2; kh++) {
#pragma unroll
    for (int i = 0; i < 4; i++) {
      float4 v = (kh == 0) ? v0[i] : v1[i];
      ushort4 h, l;
      h.x = f2bf(v.x); l.x = f2bf(v.x - bf2f(h.x));
      h.y = f2bf(v.y); l.y = f2bf(v.y - bf2f(h.y));
      h.z = f2bf(v.z); l.z = f2bf(v.z - bf2f(h.z));
      h.w = f2bf(v.w); l.w = f2bf(v.w - bf2f(h.w));
      *(ushort4*)&xh_lds[rows[i] * XS + 4 * c32] = h;
      *(ushort4*)&xl_lds[rows[i] * XS + 4 * c32] = l;
    }
    __syncthreads();

    const ushort_t* wb = Wsw + ((size_t)(wv * 2 + kh) * 8) * 2 * 512 + lane * 8;
#pragma unroll
    for (int tc = 0; tc < 2; tc++) {
      bf16x8 wbh[4], wbl[4];
#pragma unroll
      for (int t4 = 0; t4 < 4; t4++) {
        wbh[t4] = *(const bf16x8*)(wb + (size_t)(tc * 4 + t4) * 1024);
        wbl[t4] = *(const bf16x8*)(wb + (size_t)(tc * 4 + t4) * 1024 + 512);
      }
#pragma unroll
      for (int t4 = 0; t4 < 4; t4++) {
        int ko = (tc * 4 + t4) * 16 + fq * 8;
        bf16x8 ah = *(const bf16x8*)&xh_lds[fm * XS + ko];
        bf16x8 al = *(const bf16x8*)&xl_lds[fm * XS + ko];
        acc = __builtin_amdgcn_mfma_f32_32x32x16_bf16(ah, wbh[t4], acc, 0, 0, 0);
        acc = __builtin_amdgcn_mfma_f32_32x32x16_bf16(ah, wbl[t4], acc, 0, 0, 0);
        acc = __builtin_amdgcn_mfma_f32_32x32x16_bf16(al, wbh[t4], acc, 0, 0, 0);
      }
    }
    if (kh == 0) __syncthreads();  // all reads done before buffer reuse
  }

  int j = wv * 32 + fm;
  float bv = bias[j];
#pragma unroll
  for (int q = 0; q < 16; q++) {
    int row = (q & 3) + 8 * (q >> 2) + 4 * fq;
    int node = node0 + row;
    if (node < N_NODES)
      OutT[(size_t)node * D + j] = f2bf(acc[q] + bv);  // UNSCALED
  }
}

// ---------------- gather primitives ----------------
__device__ __forceinline__ void fma8(float acc[8], uint4 u, float f) {
  acc[0] = fmaf(bflo(u.x), f, acc[0]);
  acc[1] = fmaf(bfhi(u.x), f, acc[1]);
  acc[2] = fmaf(bflo(u.y), f, acc[2]);
  acc[3] = fmaf(bfhi(u.y), f, acc[3]);
  acc[4] = fmaf(bflo(u.z), f, acc[4]);
  acc[5] = fmaf(bfhi(u.z), f, acc[5]);
  acc[6] = fmaf(bflo(u.w), f, acc[6]);
  acc[7] = fmaf(bfhi(u.w), f, acc[7]);
}
__device__ __forceinline__ void addu4(float acc[8], uint4 u) {
  acc[0] += bflo(u.x);
  acc[1] += bfhi(u.x);
  acc[2] += bflo(u.y);
  acc[3] += bfhi(u.y);
  acc[4] += bflo(u.z);
  acc[5] += bfhi(u.z);
  acc[6] += bflo(u.w);
  acc[7] += bfhi(u.w);
}

__device__ __forceinline__ uint4 ldrow(const char* tbase, int s, int h) {
  return *(const uint4*)(tbase + (((unsigned)s << 8) + ((unsigned)h << 4)));
}

// scaled burst (round-10 measured-good form: f[8] alongside u[8])
__device__ __forceinline__ void burst8s(const char* tbase, int sidx, float scl,
                                        int gbase, int qoff, int h, float acc[8]) {
  uint4 u[8];
  float f[8];
#pragma unroll
  for (int q = 0; q < 8; q++) {
    int s = __shfl(sidx, gbase + qoff + q);
    f[q] = __shfl(scl, gbase + qoff + q);
    u[q] = ldrow(tbase, s, h);
  }
#pragma unroll
  for (int q = 0; q < 8; q++) fma8(acc, u[q], f[q]);
}

// plain burst: no scaling (rows pre-scaled by producer).
__device__ __forceinline__ void burst8p(const char* tbase, int sidx,
                                        int gbase, int qoff, int h, float acc[8]) {
  uint4 u[8];
#pragma unroll
  for (int q = 0; q < 8; q++) {
    int s = __shfl(sidx, gbase + qoff + q);
    u[q] = ldrow(tbase, s, h);
  }
#pragma unroll
  for (int q = 0; q < 8; q++) addu4(acc, u[q]);
}

// k3 gather: rows UNSCALED, scale by dinv[s]=rsqrt(deg[s]+1) per row.
__device__ __forceinline__ void gather_scaled(
    const char* tbase, const ushort_t* __restrict__ bucket,
    const int* __restrict__ deg, const int* __restrict__ ovf, int novf,
    int node, int degv, bool valid, int gbase, int h, float acc[8]) {
  int cnt = valid ? min(degv, BCAP) : 0;
  int sidx = (h < cnt) ? (int)bucket[node * BCAP + h] : N_NODES;
  float scl = rsqrtf((float)(deg[sidx] + 1));  // deg[N_NODES]=0 -> 1.0, row=0
  burst8s(tbase, sidx, scl, gbase, 0, h, acc);
  burst8s(tbase, sidx, scl, gbase, 8, h, acc);
  for (int b2 = 16; b2 < cnt; b2 += 16) {  // deg in (16,32]: one more batch
    int sx = (b2 + h < cnt) ? (int)bucket[node * BCAP + b2 + h] : N_NODES;
    float sc = rsqrtf((float)(deg[sx] + 1));
    burst8s(tbase, sx, sc, gbase, 0, h, acc);
    burst8s(tbase, sx, sc, gbase, 8, h, acc);
  }
  if (valid && degv > BCAP) {  // exact overflow handling (P~1e-7)
    for (int i = 0; i < novf; i++) {
      if (ovf[2 * i] == node) {
        int s = ovf[2 * i + 1];
        fma8(acc, ldrow(tbase, s, h), rsqrtf((float)(deg[s] + 1)));
      }
    }
  }
}

// k4 gather: rows PRE-SCALED by producer -> plain adds, no deg loads.
__device__ __forceinline__ void gather_plain(
    const char* tbase, const ushort_t* __restrict__ bucket,
    const int* __restrict__ ovf, int novf,
    int node, int degv, bool valid, int gbase, int h, float acc[8]) {
  int cnt = valid ? min(degv, BCAP) : 0;
  int sidx = (h < cnt) ? (int)bucket[node * BCAP + h] : N_NODES;
  burst8p(tbase, sidx, gbase, 0, h, acc);
  burst8p(tbase, sidx, gbase, 8, h, acc);
  for (int b2 = 16; b2 < cnt; b2 += 16) {
    int sx = (b2 + h < cnt) ? (int)bucket[node * BCAP + b2 + h] : N_NODES;
    burst8p(tbase, sx, gbase, 0, h, acc);
    burst8p(tbase, sx, gbase, 8, h, acc);
  }
  if (valid && degv > BCAP) {
    for (int i = 0; i < novf; i++) {
      if (ovf[2 * i] == node) addu4(acc, ldrow(tbase, ovf[2 * i + 1], h));
    }
  }
}

// ---------------- k3: FUSED aggregate1 + conv2-GEMM ----------------
// Round-10 structure (both gathers back-to-back, epilogues after) with ONE
// change: C-write pre-scales T2 by dinv[node] (coalesced deg loads) so k4's
// gather is scale-free.
__global__ __launch_bounds__(256) void k_agg_gemm(
    const ushort_t* __restrict__ t1, const int* __restrict__ deg,
    const ushort_t* __restrict__ bucket, const int* __restrict__ ovfc,
    const int* __restrict__ ovf, const float* __restrict__ b1f,
    const ushort_t* __restrict__ Wsw, ushort_t* __restrict__ OutT2) {
  constexpr int XS = 136;
  __shared__ __align__(16) ushort_t xh_lds[32 * XS];
  __shared__ __align__(16) ushort_t xl_lds[32 * XS];

  int tid = threadIdx.x;
  int lane = tid & 63;
  int wv = tid >> 6;
  int node0 = blockIdx.x * 32;
  int fm = lane & 31;
  int fq = lane >> 5;
  int g = lane >> 4;   // group 0..3
  int h = lane & 15;   // dim-chunk 0..15
  int gbase = lane & 48;

  const char* tb = (const char*)t1;
  float4 bA = *(const float4*)&b1f[h * 8];
  float4 bB = *(const float4*)&b1f[h * 8 + 4];
  int novf = *ovfc;

  // hoisted per-wave deg loads (8 nodes)
  int node0w = node0 + wv * 8;
  int dgl = deg[min(node0w + min(lane, 7), N_NODES - 1)];

  int nodeA = node0w + g;      // pass-0 node (wave rows 0..3)
  int nodeB = node0w + 4 + g;  // pass-1 node (wave rows 4..7)
  int degA = __shfl(dgl, g);
  int degB = __shfl(dgl, 4 + g);
  bool vA = nodeA < N_NODES, vB = nodeB < N_NODES;
  float diA = rsqrtf((float)(degA + 1));
  float diB = rsqrtf((float)(degB + 1));

  float accA[8];
#pragma unroll
  for (int q = 0; q < 8; q++) accA[q] = 0.f;
  fma8(accA, ldrow(tb, vA ? nodeA : N_NODES, h), diA);  // self * own dinv
  gather_scaled(tb, bucket, deg, ovf, novf, nodeA, degA, vA, gbase, h, accA);

  float accB[8];
#pragma unroll
  for (int q = 0; q < 8; q++) accB[q] = 0.f;
  fma8(accB, ldrow(tb, vB ? nodeB : N_NODES, h), diB);
  gather_scaled(tb, bucket, deg, ovf, novf, nodeB, degB, vB, gbase, h, accB);

  // ---- epilogues -> LDS ----
#pragma unroll
  for (int p = 0; p < 2; p++) {
    float* acc = p ? accB : accA;
    bool vv = p ? vB : vA;
    float di = p ? diB : diA;
    int row = wv * 8 + p * 4 + g;
    bf16x8 ph, pl;
    if (vv) {
      float val[8];
      val[0] = fmaxf(di * acc[0] + bA.x, 0.f);
      val[1] = fmaxf(di * acc[1] + bA.y, 0.f);
      val[2] = fmaxf(di * acc[2] + bA.z, 0.f);
      val[3] = fmaxf(di * acc[3] + bA.w, 0.f);
      val[4] = fmaxf(di * acc[4] + bB.x, 0.f);
      val[5] = fmaxf(di * acc[5] + bB.y, 0.f);
      val[6] = fmaxf(di * acc[6] + bB.z, 0.f);
      val[7] = fmaxf(di * acc[7] + bB.w, 0.f);
#pragma unroll
      for (int q = 0; q < 8; q++) {
        ushort_t hq = f2bf(val[q]);
        ph[q] = (short)hq;
        pl[q] = (short)f2bf(val[q] - bf2f(hq));
      }
    } else {
#pragma unroll
      for (int q = 0; q < 8; q++) { ph[q] = 0; pl[q] = 0; }
    }
    *(bf16x8*)&xh_lds[row * XS + h * 8] = ph;
    *(bf16x8*)&xl_lds[row * XS + h * 8] = pl;
  }
  __syncthreads();

  f32x16 acc;
#pragma unroll
  for (int q = 0; q < 16; q++) acc[q] = 0.f;
  {
    const ushort_t* wb = Wsw + ((size_t)wv * 8) * 2 * 512 + lane * 8;
#pragma unroll
    for (int tc = 0; tc < 2; tc++) {
      bf16x8 wbh[4], wbl[4];
#pragma unroll
      for (int t4 = 0; t4 < 4; t4++) {
        wbh[t4] = *(const bf16x8*)(wb + (size_t)(tc * 4 + t4) * 1024);
        wbl[t4] = *(const bf16x8*)(wb + (size_t)(tc * 4 + t4) * 1024 + 512);
      }
#pragma unroll
      for (int t4 = 0; t4 < 4; t4++) {
        int ko = (tc * 4 + t4) * 16 + fq * 8;
        bf16x8 ah = *(const bf16x8*)&xh_lds[fm * XS + ko];
        bf16x8 al = *(const bf16x8*)&xl_lds[fm * XS + ko];
        acc = __builtin_amdgcn_mfma_f32_32x32x16_bf16(ah, wbh[t4], acc, 0, 0, 0);
        acc = __builtin_amdgcn_mfma_f32_32x32x16_bf16(ah, wbl[t4], acc, 0, 0, 0);
        acc = __builtin_amdgcn_mfma_f32_32x32x16_bf16(al, wbh[t4], acc, 0, 0, 0);
      }
    }
  }
  int j = wv * 32 + fm;
#pragma unroll
  for (int q = 0; q < 16; q++) {
    int row = (q & 3) + 8 * (q >> 2) + 4 * fq;
    int node = node0 + row;
    if (node < N_NODES) {
      float di = rsqrtf((float)(deg[node] + 1));  // coalesced: contiguous nodes
      OutT2[(size_t)node * D + j] = f2bf(acc[q] * di);  // PRE-SCALED T2
    }
  }
}

// ---------------- k4: final aggregation -> fp32 out ----------------
// T2 rows are pre-scaled -> plain-add gather (no random deg loads).
__global__ __launch_bounds__(256) void k_agg_out(
    const ushort_t* __restrict__ t, const int* __restrict__ deg,
    const ushort_t* __restrict__ bucket, const int* __restrict__ ovfc,
    const int* __restrict__ ovf, const float* __restrict__ bias,
    float* __restrict__ out_f) {
  int wv = threadIdx.x >> 6;
  int lane = threadIdx.x & 63;
  int g = lane >> 4;
  int h = lane & 15;
  int gbase = lane & 48;
  int nodew = blockIdx.x * 16 + wv * 4;
  int dgl = deg[min(nodew + min(lane, 3), N_NODES - 1)];
  int node = nodew + g;
  int degn = __shfl(dgl, g);
  bool vn = node < N_NODES;
  float di = rsqrtf((float)(degn + 1));
  int novf = *ovfc;

  const char* tb = (const char*)t;
  float acc[8];
#pragma unroll
  for (int q = 0; q < 8; q++) acc[q] = 0.f;
  addu4(acc, ldrow(tb, vn ? node : N_NODES, h));  // self (already dinv-scaled)
  gather_plain(tb, bucket, ovf, novf, node, degn, vn, gbase, h, acc);

  if (!vn) return;
  float4 bA = *(const float4*)&bias[h * 8];
  float4 bB = *(const float4*)&bias[h * 8 + 4];
  float4 o0, o1;
  o0.x = di * acc[0] + bA.x;
  o0.y = di * acc[1] + bA.y;
  o0.z = di * acc[2] + bA.z;
  o0.w = di * acc[3] + bA.w;
  o1.x = di * acc[4] + bB.x;
  o1.y = di * acc[5] + bB.y;
  o1.z = di * acc[6] + bB.z;
  o1.w = di * acc[7] + bB.w;
  *(float4*)&out_f[(size_t)node * D + h * 8] = o0;
  *(float4*)&out_f[(size_t)node * D + h * 8 + 4] = o1;
}

extern "C" void kernel_launch(void* const* d_in, const int* in_sizes, int n_in,
                              void* d_out, int out_size, void* d_ws, size_t ws_size,
                              hipStream_t stream) {
  const int* tokens = (const int*)d_in[0];
  const int* edge = (const int*)d_in[1];  // [2][E]
  const float* embed = (const float*)d_in[2];
  const float* Wn = (const float*)d_in[3];
  const float* bn = (const float*)d_in[4];
  const float* w1 = (const float*)d_in[5];
  const float* b1 = (const float*)d_in[6];
  const float* w2 = (const float*)d_in[7];
  const float* b2 = (const float*)d_in[8];
  float* out = (float*)d_out;  // fp32 output

  const int* src = edge;
  const int* dst = edge + N_EDGES;

  char* ws = (char*)d_ws;
  // T1/T2 have one extra ZERO row at index N_NODES (gather padding target)
  ushort_t* T1 = (ushort_t*)ws;                  // 12,800,256 B
  ushort_t* T2 = (ushort_t*)(ws + 12800256);     // 12,800,256 B
  ushort_t* bucket = (ushort_t*)(ws + 25600512); // 3,200,000 B (50K x 32 u16)
  int* deg = (int*)(ws + 28800512);              // 200,064 B (50001 ints, pad)
  int* ovfc = (int*)(ws + 29000576);             // 128 B (isolated counter)
  int* ovf = (int*)(ws + 29000704);              // 16,384 B (2048 pairs)
  ushort_t* WcSw = (ushort_t*)(ws + 29017088);   // 131,072 B (swizzled hi/lo)
  ushort_t* W2Sw = (ushort_t*)(ws + 29148160);   // 65,536 B (swizzled hi/lo)
  float* bias_ws = (float*)(ws + 29213696);      // bc | b1 | b2 (1,536 B)
  float* bcf = bias_ws;
  float* b1f = bias_ws + 128;
  float* b2f = bias_ws + 256;

  // zero deg (incl. deg[N_NODES]=0 for dummy-row scale) + overflow counter
  hipMemsetAsync(deg, 0, 200192, stream);

  // --- k1: weight prep only (small, fast) ---
  k_wprep<<<194, 256, 0, stream>>>(
      Wn, w1, bn, w2, b1, b2, WcSw, W2Sw, bias_ws, T1, T2);

  // --- k2: conv1 T1 = gather(e)@Wc^T + bc (UNSCALED) || edge fill ---
  k_gemm_fill<<<MIX_BLOCKS, 256, 0, stream>>>(
      embed, tokens, WcSw, bcf, T1, src, dst, deg, bucket, ovfc, ovf);

  // --- k3: x1 = relu(dinv*agg_scaled(T1)+b1); T2 = dinv*(x1@w2^T) ---
  k_agg_gemm<<<GEMM_BLOCKS, 256, 0, stream>>>(
      T1, deg, bucket, ovfc, ovf, b1f, W2Sw, T2);

  // --- k4: out = dinv*agg_plain(T2) + b2 (fp32) ---
  k_agg_out<<<OUT_CHUNKS, 256, 0, stream>>>(
      T2, deg, bucket, ovfc, ovf, b2f, out);
}

// Round 13
// 215.383 us; speedup vs baseline: 1.0261x; 1.0141x over previous
//
#include <hip/hip_runtime.h>
#include <hip/hip_bf16.h>

#define N_NODES 50000
#define N_EDGES 600000
#define D_IN 256
#define D 128

#define GEMM_BLOCKS ((N_NODES + 31) / 32)    // 1563
#define EDGE_BLOCKS ((N_EDGES + 255) / 256)  // 2344
#define MIX_BLOCKS 3910                      // 782 groups x 5 (2 gemm + 3 fill)
#define OUT_CHUNKS (N_NODES / 16)            // 3125
#define BCAP 32                              // bucket capacity per node
#define OVF_CAP 2048                         // overflow entries (P(use)~1e-7)

typedef unsigned short ushort_t;
typedef __attribute__((ext_vector_type(8))) short bf16x8;
typedef __attribute__((ext_vector_type(16))) float f32x16;

__device__ __forceinline__ float bf2f(ushort_t u) {
  union { unsigned int i; float f; } v;
  v.i = ((unsigned int)u) << 16;
  return v.f;
}
__device__ __forceinline__ ushort_t f2bf(float f) {
  union { float f; unsigned int i; } v;
  v.f = f;
  unsigned int x = v.i;
  unsigned int r = (x + 0x7FFFu + ((x >> 16) & 1u)) >> 16;  // RNE
  return (ushort_t)r;
}
__device__ __forceinline__ float bflo(unsigned int u) {
  union { unsigned int i; float f; } v;
  v.i = u << 16;
  return v.f;
}
__device__ __forceinline__ float bfhi(unsigned int u) {
  union { unsigned int i; float f; } v;
  v.i = u & 0xFFFF0000u;
  return v.f;
}

// Swizzled-W addressing: element (j,k) of [128,KDIM] W, hi/lo split:
//   wv=j>>5, fm=j&31, kh=k>>7, t=(k>>4)&7, fq=(k>>3)&1, c=k&7, lane=fq*32+fm
//   addr = (((wv*(KDIM/128)+kh)*8 + t)*2 + hl)*512 + lane*8 + c   [ushorts]

// ---------------- k1: weight prep only (no edge work) ----------------
__global__ __launch_bounds__(256) void k_wprep(
    const float* __restrict__ wn, const float* __restrict__ w1,
    const float* __restrict__ bn, const float* __restrict__ w2,
    const float* __restrict__ b1, const float* __restrict__ b2,
    ushort_t* __restrict__ WcSw, ushort_t* __restrict__ W2Sw,
    float* __restrict__ bias_ws,
    ushort_t* __restrict__ T1z, ushort_t* __restrict__ T2z) {
  int bid = blockIdx.x;
  int tid = threadIdx.x;
  float* bcf = bias_ws;
  float* b1f = bias_ws + 128;
  float* b2f = bias_ws + 256;
  if (bid < 128) {
    int j = bid;
    int k = tid;
    float acc = 0.f;
#pragma unroll 8
    for (int m = 0; m < 128; m++)
      acc += w1[j * 128 + m] * wn[m * 256 + k];
    ushort_t h = f2bf(acc);
    ushort_t l = f2bf(acc - bf2f(h));
    int wv = j >> 5, fm = j & 31;
    int kh = k >> 7, t = (k >> 4) & 7, fq = (k >> 3) & 1, c = k & 7;
    int lane = fq * 32 + fm;
    int base = ((wv * 2 + kh) * 8 + t) * 2 * 512 + lane * 8 + c;  // KH=2
    WcSw[base] = h;
    WcSw[base + 512] = l;
    if (k == 0) {
      float s = 0.f;
      for (int m = 0; m < 128; m++) s += w1[j * 128 + m] * bn[m];
      bcf[j] = s;
    }
  } else if (bid < 193) {
    int i = (bid - 128) * 256 + tid;
    if (i < 16384) {
      float v = w2[i];
      ushort_t h = f2bf(v);
      ushort_t l = f2bf(v - bf2f(h));
      int j = i >> 7, k = i & 127;
      int wv = j >> 5, fm = j & 31;
      int t = (k >> 4) & 7, fq = (k >> 3) & 1, c = k & 7;
      int lane = fq * 32 + fm;
      int base = (wv * 8 + t) * 2 * 512 + lane * 8 + c;  // KH=1
      W2Sw[base] = h;
      W2Sw[base + 512] = l;
    } else if (i < 16512) {
      b1f[i - 16384] = b1[i - 16384];
    } else if (i < 16640) {
      b2f[i - 16512] = b2[i - 16512];
    }
  } else {
    // zero the shared dummy row T[N_NODES] (gather padding target)
    unsigned int* z1 = (unsigned int*)&T1z[(size_t)N_NODES * D];
    unsigned int* z2 = (unsigned int*)&T2z[(size_t)N_NODES * D];
    if (tid < 64) z1[tid] = 0u;
    else if (tid < 128) z2[tid - 64] = 0u;
  }
}

// ---------------- k2: conv1-GEMM (UNSCALED T1) || edge fill ----------------
// T1 has no dinv dependency -> edge fill (deg atomic + ushort bucket) runs
// CONCURRENTLY in the same dispatch, interleaved 2:3.
__global__ __launch_bounds__(256) void k_gemm_fill(
    const float* __restrict__ Xv, const int* __restrict__ tokens,
    const ushort_t* __restrict__ Wsw, const float* __restrict__ bias,
    ushort_t* __restrict__ OutT,
    const int* __restrict__ src, const int* __restrict__ dst,
    int* __restrict__ deg, ushort_t* __restrict__ bucket,
    int* __restrict__ ovfc, int* __restrict__ ovf) {
  constexpr int XS = 136;
  __shared__ __align__(16) ushort_t xh_lds[32 * XS];
  __shared__ __align__(16) ushort_t xl_lds[32 * XS];

  int bid = blockIdx.x;
  int tid = threadIdx.x;
  int grp = bid / 5, r = bid % 5;
  if (r >= 2) {
    // ---- fill path: deg atomic gives the slot; ushort bucket row = 64B ----
    int c = grp * 3 + (r - 2);
    if (c >= EDGE_BLOCKS) return;
    int e = c * 256 + tid;
    if (e < N_EDGES) {
      int d = dst[e];
      int s = src[e];
      int pos = atomicAdd(&deg[d], 1);
      if (pos < BCAP) {
        bucket[d * BCAP + pos] = (ushort_t)s;
      } else {
        int oi = atomicAdd(ovfc, 1);
        if (oi < OVF_CAP) {
          ovf[2 * oi] = d;
          ovf[2 * oi + 1] = s;
        }
      }
    }
    return;
  }

  // ---- GEMM path ----
  int t = grp * 2 + r;
  if (t >= GEMM_BLOCKS) return;
  int lane = tid & 63;
  int wv = tid >> 6;
  int node0 = t * 32;
  int fm = lane & 31;
  int fq = lane >> 5;
  int r8 = tid >> 5;   // 0..7
  int c32 = tid & 31;  // 0..31

  const char* xb = (const char*)Xv;
  float4 v0[4], v1[4];
  int rows[4];
#pragma unroll
  for (int i = 0; i < 4; i++) {
    rows[i] = r8 * 4 + i;
    int tk = tokens[min(node0 + rows[i], N_NODES - 1)];
    unsigned off = (unsigned)tk * (D_IN * 4) + (unsigned)c32 * 16;
    v0[i] = *(const float4*)(xb + off);
    v1[i] = *(const float4*)(xb + off + 512);
  }

  f32x16 acc;
#pragma unroll
  for (int q = 0; q < 16; q++) acc[q] = 0.f;

#pragma unroll
  for (int kh = 0; kh < 2; kh++) {
#pragma unroll
    for (int i = 0; i < 4; i++) {
      float4 v = (kh == 0) ? v0[i] : v1[i];
      ushort4 h, l;
      h.x = f2bf(v.x); l.x = f2bf(v.x - bf2f(h.x));
      h.y = f2bf(v.y); l.y = f2bf(v.y - bf2f(h.y));
      h.z = f2bf(v.z); l.z = f2bf(v.z - bf2f(h.z));
      h.w = f2bf(v.w); l.w = f2bf(v.w - bf2f(h.w));
      *(ushort4*)&xh_lds[rows[i] * XS + 4 * c32] = h;
      *(ushort4*)&xl_lds[rows[i] * XS + 4 * c32] = l;
    }
    __syncthreads();

    const ushort_t* wb = Wsw + ((size_t)(wv * 2 + kh) * 8) * 2 * 512 + lane * 8;
#pragma unroll
    for (int tc = 0; tc < 2; tc++) {
      bf16x8 wbh[4], wbl[4];
#pragma unroll
      for (int t4 = 0; t4 < 4; t4++) {
        wbh[t4] = *(const bf16x8*)(wb + (size_t)(tc * 4 + t4) * 1024);
        wbl[t4] = *(const bf16x8*)(wb + (size_t)(tc * 4 + t4) * 1024 + 512);
      }
#pragma unroll
      for (int t4 = 0; t4 < 4; t4++) {
        int ko = (tc * 4 + t4) * 16 + fq * 8;
        bf16x8 ah = *(const bf16x8*)&xh_lds[fm * XS + ko];
        bf16x8 al = *(const bf16x8*)&xl_lds[fm * XS + ko];
        acc = __builtin_amdgcn_mfma_f32_32x32x16_bf16(ah, wbh[t4], acc, 0, 0, 0);
        acc = __builtin_amdgcn_mfma_f32_32x32x16_bf16(ah, wbl[t4], acc, 0, 0, 0);
        acc = __builtin_amdgcn_mfma_f32_32x32x16_bf16(al, wbh[t4], acc, 0, 0, 0);
      }
    }
    if (kh == 0) __syncthreads();  // all reads done before buffer reuse
  }

  int j = wv * 32 + fm;
  float bv = bias[j];
#pragma unroll
  for (int q = 0; q < 16; q++) {
    int row = (q & 3) + 8 * (q >> 2) + 4 * fq;
    int node = node0 + row;
    if (node < N_NODES)
      OutT[(size_t)node * D + j] = f2bf(acc[q] + bv);  // UNSCALED
  }
}

// ---------------- gather primitives ----------------
__device__ __forceinline__ void fma8(float acc[8], uint4 u, float f) {
  acc[0] = fmaf(bflo(u.x), f, acc[0]);
  acc[1] = fmaf(bfhi(u.x), f, acc[1]);
  acc[2] = fmaf(bflo(u.y), f, acc[2]);
  acc[3] = fmaf(bfhi(u.y), f, acc[3]);
  acc[4] = fmaf(bflo(u.z), f, acc[4]);
  acc[5] = fmaf(bfhi(u.z), f, acc[5]);
  acc[6] = fmaf(bflo(u.w), f, acc[6]);
  acc[7] = fmaf(bfhi(u.w), f, acc[7]);
}
__device__ __forceinline__ void addu4(float acc[8], uint4 u) {
  acc[0] += bflo(u.x);
  acc[1] += bfhi(u.x);
  acc[2] += bflo(u.y);
  acc[3] += bfhi(u.y);
  acc[4] += bflo(u.z);
  acc[5] += bfhi(u.z);
  acc[6] += bflo(u.w);
  acc[7] += bfhi(u.w);
}

__device__ __forceinline__ uint4 ldrow(const char* tbase, int s, int h) {
  return *(const uint4*)(tbase + (((unsigned)s << 8) + ((unsigned)h << 4)));
}

// scaled burst: per-row scale f alongside u (round-10 measured-good form)
__device__ __forceinline__ void burst8s(const char* tbase, int sidx, float scl,
                                        int gbase, int qoff, int h, float acc[8]) {
  uint4 u[8];
  float f[8];
#pragma unroll
  for (int q = 0; q < 8; q++) {
    int s = __shfl(sidx, gbase + qoff + q);
    f[q] = __shfl(scl, gbase + qoff + q);
    u[q] = ldrow(tbase, s, h);
  }
#pragma unroll
  for (int q = 0; q < 8; q++) fma8(acc, u[q], f[q]);
}

// k3/k4 gather: rows UNSCALED, scale by dinv[s]=rsqrt(deg[s]+1) per row.
__device__ __forceinline__ void gather_scaled(
    const char* tbase, const ushort_t* __restrict__ bucket,
    const int* __restrict__ deg, const int* __restrict__ ovf, int novf,
    int node, int degv, bool valid, int gbase, int h, float acc[8]) {
  int cnt = valid ? min(degv, BCAP) : 0;
  int sidx = (h < cnt) ? (int)bucket[node * BCAP + h] : N_NODES;
  float scl = rsqrtf((float)(deg[sidx] + 1));  // deg[N_NODES]=0 -> 1.0, row=0
  burst8s(tbase, sidx, scl, gbase, 0, h, acc);
  burst8s(tbase, sidx, scl, gbase, 8, h, acc);
  for (int b2 = 16; b2 < cnt; b2 += 16) {  // deg in (16,32]: one more batch
    int sx = (b2 + h < cnt) ? (int)bucket[node * BCAP + b2 + h] : N_NODES;
    float sc = rsqrtf((float)(deg[sx] + 1));
    burst8s(tbase, sx, sc, gbase, 0, h, acc);
    burst8s(tbase, sx, sc, gbase, 8, h, acc);
  }
  if (valid && degv > BCAP) {  // exact overflow handling (P~1e-7)
    for (int i = 0; i < novf; i++) {
      if (ovf[2 * i] == node) {
        int s = ovf[2 * i + 1];
        fma8(acc, ldrow(tbase, s, h), rsqrtf((float)(deg[s] + 1)));
      }
    }
  }
}

// epilogue: bias+relu+hi/lo pack -> LDS
__device__ __forceinline__ void epi_lds(
    const float acc[8], bool vv, float di, float4 bA, float4 bB,
    int row, int h, ushort_t* xh_lds, ushort_t* xl_lds) {
  constexpr int XS = 136;
  bf16x8 ph, pl;
  if (vv) {
    float val[8];
    val[0] = fmaxf(di * acc[0] + bA.x, 0.f);
    val[1] = fmaxf(di * acc[1] + bA.y, 0.f);
    val[2] = fmaxf(di * acc[2] + bA.z, 0.f);
    val[3] = fmaxf(di * acc[3] + bA.w, 0.f);
    val[4] = fmaxf(di * acc[4] + bB.x, 0.f);
    val[5] = fmaxf(di * acc[5] + bB.y, 0.f);
    val[6] = fmaxf(di * acc[6] + bB.z, 0.f);
    val[7] = fmaxf(di * acc[7] + bB.w, 0.f);
#pragma unroll
    for (int q = 0; q < 8; q++) {
      ushort_t hq = f2bf(val[q]);
      ph[q] = (short)hq;
      pl[q] = (short)f2bf(val[q] - bf2f(hq));
    }
  } else {
#pragma unroll
    for (int q = 0; q < 8; q++) { ph[q] = 0; pl[q] = 0; }
  }
  *(bf16x8*)&xh_lds[row * XS + h * 8] = ph;
  *(bf16x8*)&xl_lds[row * XS + h * 8] = pl;
}

// ---------------- k3: FUSED aggregate1 + conv2-GEMM ----------------
// Round-10 measured-best structure: both gathers back-to-back (accA/accB
// live together -> both latency chains in flight), epilogues after,
// T2 written UNSCALED (k4 applies per-row dinv).
__global__ __launch_bounds__(256) void k_agg_gemm(
    const ushort_t* __restrict__ t1, const int* __restrict__ deg,
    const ushort_t* __restrict__ bucket, const int* __restrict__ ovfc,
    const int* __restrict__ ovf, const float* __restrict__ b1f,
    const ushort_t* __restrict__ Wsw, ushort_t* __restrict__ OutT2) {
  constexpr int XS = 136;
  __shared__ __align__(16) ushort_t xh_lds[32 * XS];
  __shared__ __align__(16) ushort_t xl_lds[32 * XS];

  int tid = threadIdx.x;
  int lane = tid & 63;
  int wv = tid >> 6;
  int node0 = blockIdx.x * 32;
  int fm = lane & 31;
  int fq = lane >> 5;
  int g = lane >> 4;   // group 0..3
  int h = lane & 15;   // dim-chunk 0..15
  int gbase = lane & 48;

  const char* tb = (const char*)t1;
  float4 bA = *(const float4*)&b1f[h * 8];
  float4 bB = *(const float4*)&b1f[h * 8 + 4];
  int novf = *ovfc;

  // hoisted per-wave deg loads (8 nodes)
  int node0w = node0 + wv * 8;
  int dgl = deg[min(node0w + min(lane, 7), N_NODES - 1)];

  int nodeA = node0w + g;      // pass-0 node (wave rows 0..3)
  int nodeB = node0w + 4 + g;  // pass-1 node (wave rows 4..7)
  int degA = __shfl(dgl, g);
  int degB = __shfl(dgl, 4 + g);
  bool vA = nodeA < N_NODES, vB = nodeB < N_NODES;
  float diA = rsqrtf((float)(degA + 1));
  float diB = rsqrtf((float)(degB + 1));

  float accA[8];
#pragma unroll
  for (int q = 0; q < 8; q++) accA[q] = 0.f;
  fma8(accA, ldrow(tb, vA ? nodeA : N_NODES, h), diA);  // self * own dinv
  gather_scaled(tb, bucket, deg, ovf, novf, nodeA, degA, vA, gbase, h, accA);

  float accB[8];
#pragma unroll
  for (int q = 0; q < 8; q++) accB[q] = 0.f;
  fma8(accB, ldrow(tb, vB ? nodeB : N_NODES, h), diB);
  gather_scaled(tb, bucket, deg, ovf, novf, nodeB, degB, vB, gbase, h, accB);

  // ---- epilogues -> LDS ----
  epi_lds(accA, vA, diA, bA, bB, wv * 8 + g, h, xh_lds, xl_lds);
  epi_lds(accB, vB, diB, bA, bB, wv * 8 + 4 + g, h, xh_lds, xl_lds);
  __syncthreads();

  f32x16 acc;
#pragma unroll
  for (int q = 0; q < 16; q++) acc[q] = 0.f;
  {
    const ushort_t* wb = Wsw + ((size_t)wv * 8) * 2 * 512 + lane * 8;
#pragma unroll
    for (int tc = 0; tc < 2; tc++) {
      bf16x8 wbh[4], wbl[4];
#pragma unroll
      for (int t4 = 0; t4 < 4; t4++) {
        wbh[t4] = *(const bf16x8*)(wb + (size_t)(tc * 4 + t4) * 1024);
        wbl[t4] = *(const bf16x8*)(wb + (size_t)(tc * 4 + t4) * 1024 + 512);
      }
#pragma unroll
      for (int t4 = 0; t4 < 4; t4++) {
        int ko = (tc * 4 + t4) * 16 + fq * 8;
        bf16x8 ah = *(const bf16x8*)&xh_lds[fm * XS + ko];
        bf16x8 al = *(const bf16x8*)&xl_lds[fm * XS + ko];
        acc = __builtin_amdgcn_mfma_f32_32x32x16_bf16(ah, wbh[t4], acc, 0, 0, 0);
        acc = __builtin_amdgcn_mfma_f32_32x32x16_bf16(ah, wbl[t4], acc, 0, 0, 0);
        acc = __builtin_amdgcn_mfma_f32_32x32x16_bf16(al, wbh[t4], acc, 0, 0, 0);
      }
    }
  }
  int j = wv * 32 + fm;
#pragma unroll
  for (int q = 0; q < 16; q++) {
    int row = (q & 3) + 8 * (q >> 2) + 4 * fq;
    int node = node0 + row;
    if (node < N_NODES)
      OutT2[(size_t)node * D + j] = f2bf(acc[q]);  // UNSCALED
  }
}

// ---------------- k4: final aggregation -> fp32 out ----------------
__global__ __launch_bounds__(256) void k_agg_out(
    const ushort_t* __restrict__ t, const int* __restrict__ deg,
    const ushort_t* __restrict__ bucket, const int* __restrict__ ovfc,
    const int* __restrict__ ovf, const float* __restrict__ bias,
    float* __restrict__ out_f) {
  int wv = threadIdx.x >> 6;
  int lane = threadIdx.x & 63;
  int g = lane >> 4;
  int h = lane & 15;
  int gbase = lane & 48;
  int nodew = blockIdx.x * 16 + wv * 4;
  int dgl = deg[min(nodew + min(lane, 3), N_NODES - 1)];
  int node = nodew + g;
  int degn = __shfl(dgl, g);
  bool vn = node < N_NODES;
  float di = rsqrtf((float)(degn + 1));
  int novf = *ovfc;

  const char* tb = (const char*)t;
  float acc[8];
#pragma unroll
  for (int q = 0; q < 8; q++) acc[q] = 0.f;
  fma8(acc, ldrow(tb, vn ? node : N_NODES, h), di);  // self * own dinv
  gather_scaled(tb, bucket, deg, ovf, novf, node, degn, vn, gbase, h, acc);

  if (!vn) return;
  float4 bA = *(const float4*)&bias[h * 8];
  float4 bB = *(const float4*)&bias[h * 8 + 4];
  float4 o0, o1;
  o0.x = di * acc[0] + bA.x;
  o0.y = di * acc[1] + bA.y;
  o0.z = di * acc[2] + bA.z;
  o0.w = di * acc[3] + bA.w;
  o1.x = di * acc[4] + bB.x;
  o1.y = di * acc[5] + bB.y;
  o1.z = di * acc[6] + bB.z;
  o1.w = di * acc[7] + bB.w;
  *(float4*)&out_f[(size_t)node * D + h * 8] = o0;
  *(float4*)&out_f[(size_t)node * D + h * 8 + 4] = o1;
}

extern "C" void kernel_launch(void* const* d_in, const int* in_sizes, int n_in,
                              void* d_out, int out_size, void* d_ws, size_t ws_size,
                              hipStream_t stream) {
  const int* tokens = (const int*)d_in[0];
  const int* edge = (const int*)d_in[1];  // [2][E]
  const float* embed = (const float*)d_in[2];
  const float* Wn = (const float*)d_in[3];
  const float* bn = (const float*)d_in[4];
  const float* w1 = (const float*)d_in[5];
  const float* b1 = (const float*)d_in[6];
  const float* w2 = (const float*)d_in[7];
  const float* b2 = (const float*)d_in[8];
  float* out = (float*)d_out;  // fp32 output

  const int* src = edge;
  const int* dst = edge + N_EDGES;

  char* ws = (char*)d_ws;
  // T1/T2 have one extra ZERO row at index N_NODES (gather padding target)
  ushort_t* T1 = (ushort_t*)ws;                  // 12,800,256 B
  ushort_t* T2 = (ushort_t*)(ws + 12800256);     // 12,800,256 B
  ushort_t* bucket = (ushort_t*)(ws + 25600512); // 3,200,000 B (50K x 32 u16)
  int* deg = (int*)(ws + 28800512);              // 200,064 B (50001 ints, pad)
  int* ovfc = (int*)(ws + 29000576);             // 128 B (isolated counter)
  int* ovf = (int*)(ws + 29000704);              // 16,384 B (2048 pairs)
  ushort_t* WcSw = (ushort_t*)(ws + 29017088);   // 131,072 B (swizzled hi/lo)
  ushort_t* W2Sw = (ushort_t*)(ws + 29148160);   // 65,536 B (swizzled hi/lo)
  float* bias_ws = (float*)(ws + 29213696);      // bc | b1 | b2 (1,536 B)
  float* bcf = bias_ws;
  float* b1f = bias_ws + 128;
  float* b2f = bias_ws + 256;

  // zero deg (incl. deg[N_NODES]=0 for dummy-row scale) + overflow counter
  hipMemsetAsync(deg, 0, 200192, stream);

  // --- k1: weight prep only (small, fast) ---
  k_wprep<<<194, 256, 0, stream>>>(
      Wn, w1, bn, w2, b1, b2, WcSw, W2Sw, bias_ws, T1, T2);

  // --- k2: conv1 T1 = gather(e)@Wc^T + bc (UNSCALED) || edge fill ---
  k_gemm_fill<<<MIX_BLOCKS, 256, 0, stream>>>(
      embed, tokens, WcSw, bcf, T1, src, dst, deg, bucket, ovfc, ovf);

  // --- k3: x1 = relu(dinv*agg_scaled(T1)+b1); T2 = x1@w2^T (UNSCALED) ---
  k_agg_gemm<<<GEMM_BLOCKS, 256, 0, stream>>>(
      T1, deg, bucket, ovfc, ovf, b1f, W2Sw, T2);

  // --- k4: out = dinv*agg_scaled(T2) + b2 (fp32) ---
  k_agg_out<<<OUT_CHUNKS, 256, 0, stream>>>(
      T2, deg, bucket, ovfc, ovf, b2f, out);
}

// Round 14
// 214.510 us; speedup vs baseline: 1.0303x; 1.0041x over previous
//
#include <hip/hip_runtime.h>
#include <hip/hip_bf16.h>

#define N_NODES 50000
#define N_EDGES 600000
#define D_IN 256
#define D 128

#define GEMM_BLOCKS ((N_NODES + 31) / 32)    // 1563
#define EDGE_BLOCKS ((N_EDGES + 255) / 256)  // 2344
#define MIX_BLOCKS 3910                      // 782 groups x 5 (2 gemm + 3 fill)
#define OUT_CHUNKS (N_NODES / 16)            // 3125
#define BCAP 32                              // bucket capacity per node
#define OVF_CAP 2048                         // overflow entries (P(use)~1e-7)
#define ZERO_INTS 50048                      // deg[50001]+pad+ovfc (200,192 B)
#define ZERO_BLOCKS 49                       // 49 x 1024 ints >= 50048

typedef unsigned short ushort_t;
typedef __attribute__((ext_vector_type(8))) short bf16x8;
typedef __attribute__((ext_vector_type(16))) float f32x16;

__device__ __forceinline__ float bf2f(ushort_t u) {
  union { unsigned int i; float f; } v;
  v.i = ((unsigned int)u) << 16;
  return v.f;
}
__device__ __forceinline__ ushort_t f2bf(float f) {
  union { float f; unsigned int i; } v;
  v.f = f;
  unsigned int x = v.i;
  unsigned int r = (x + 0x7FFFu + ((x >> 16) & 1u)) >> 16;  // RNE
  return (ushort_t)r;
}
__device__ __forceinline__ float bflo(unsigned int u) {
  union { unsigned int i; float f; } v;
  v.i = u << 16;
  return v.f;
}
__device__ __forceinline__ float bfhi(unsigned int u) {
  union { unsigned int i; float f; } v;
  v.i = u & 0xFFFF0000u;
  return v.f;
}

// Swizzled-W addressing: element (j,k) of [128,KDIM] W, hi/lo split:
//   wv=j>>5, fm=j&31, kh=k>>7, t=(k>>4)&7, fq=(k>>3)&1, c=k&7, lane=fq*32+fm
//   addr = (((wv*(KDIM/128)+kh)*8 + t)*2 + hl)*512 + lane*8 + c   [ushorts]

// ---------------- k1: weight prep + deg-region zeroing ----------------
// The deg/ovfc zeroing blocks replace the separate hipMemsetAsync dispatch
// (saves one launch+drain boundary; ordering vs k2 is unchanged since k1
// completes before k2 on the stream).
__global__ __launch_bounds__(256) void k_wprep(
    const float* __restrict__ wn, const float* __restrict__ w1,
    const float* __restrict__ bn, const float* __restrict__ w2,
    const float* __restrict__ b1, const float* __restrict__ b2,
    ushort_t* __restrict__ WcSw, ushort_t* __restrict__ W2Sw,
    float* __restrict__ bias_ws,
    ushort_t* __restrict__ T1z, ushort_t* __restrict__ T2z,
    int* __restrict__ degz) {
  int bid = blockIdx.x;
  int tid = threadIdx.x;
  float* bcf = bias_ws;
  float* b1f = bias_ws + 128;
  float* b2f = bias_ws + 256;
  if (bid < 128) {
    int j = bid;
    int k = tid;
    float acc = 0.f;
#pragma unroll 8
    for (int m = 0; m < 128; m++)
      acc += w1[j * 128 + m] * wn[m * 256 + k];
    ushort_t h = f2bf(acc);
    ushort_t l = f2bf(acc - bf2f(h));
    int wv = j >> 5, fm = j & 31;
    int kh = k >> 7, t = (k >> 4) & 7, fq = (k >> 3) & 1, c = k & 7;
    int lane = fq * 32 + fm;
    int base = ((wv * 2 + kh) * 8 + t) * 2 * 512 + lane * 8 + c;  // KH=2
    WcSw[base] = h;
    WcSw[base + 512] = l;
    if (k == 0) {
      float s = 0.f;
      for (int m = 0; m < 128; m++) s += w1[j * 128 + m] * bn[m];
      bcf[j] = s;
    }
  } else if (bid < 193) {
    int i = (bid - 128) * 256 + tid;
    if (i < 16384) {
      float v = w2[i];
      ushort_t h = f2bf(v);
      ushort_t l = f2bf(v - bf2f(h));
      int j = i >> 7, k = i & 127;
      int wv = j >> 5, fm = j & 31;
      int t = (k >> 4) & 7, fq = (k >> 3) & 1, c = k & 7;
      int lane = fq * 32 + fm;
      int base = (wv * 8 + t) * 2 * 512 + lane * 8 + c;  // KH=1
      W2Sw[base] = h;
      W2Sw[base + 512] = l;
    } else if (i < 16512) {
      b1f[i - 16384] = b1[i - 16384];
    } else if (i < 16640) {
      b2f[i - 16512] = b2[i - 16512];
    }
  } else if (bid == 193) {
    // zero the shared dummy row T[N_NODES] (gather padding target)
    unsigned int* z1 = (unsigned int*)&T1z[(size_t)N_NODES * D];
    unsigned int* z2 = (unsigned int*)&T2z[(size_t)N_NODES * D];
    if (tid < 64) z1[tid] = 0u;
    else if (tid < 128) z2[tid - 64] = 0u;
  } else {
    // zero deg + pad + ovfc (int4 = 16B per thread)
    int idx = (bid - 194) * 1024 + tid * 4;
    if (idx < ZERO_INTS) {
      int4 z; z.x = 0; z.y = 0; z.z = 0; z.w = 0;
      *(int4*)&degz[idx] = z;
    }
  }
}

// ---------------- k2: conv1-GEMM (UNSCALED T1) || edge fill ----------------
// T1 has no dinv dependency -> edge fill (deg atomic + ushort bucket) runs
// CONCURRENTLY in the same dispatch, interleaved 2:3.
__global__ __launch_bounds__(256) void k_gemm_fill(
    const float* __restrict__ Xv, const int* __restrict__ tokens,
    const ushort_t* __restrict__ Wsw, const float* __restrict__ bias,
    ushort_t* __restrict__ OutT,
    const int* __restrict__ src, const int* __restrict__ dst,
    int* __restrict__ deg, ushort_t* __restrict__ bucket,
    int* __restrict__ ovfc, int* __restrict__ ovf) {
  constexpr int XS = 136;
  __shared__ __align__(16) ushort_t xh_lds[32 * XS];
  __shared__ __align__(16) ushort_t xl_lds[32 * XS];

  int bid = blockIdx.x;
  int tid = threadIdx.x;
  int grp = bid / 5, r = bid % 5;
  if (r >= 2) {
    // ---- fill path: deg atomic gives the slot; ushort bucket row = 64B ----
    int c = grp * 3 + (r - 2);
    if (c >= EDGE_BLOCKS) return;
    int e = c * 256 + tid;
    if (e < N_EDGES) {
      int d = dst[e];
      int s = src[e];
      int pos = atomicAdd(&deg[d], 1);
      if (pos < BCAP) {
        bucket[d * BCAP + pos] = (ushort_t)s;
      } else {
        int oi = atomicAdd(ovfc, 1);
        if (oi < OVF_CAP) {
          ovf[2 * oi] = d;
          ovf[2 * oi + 1] = s;
        }
      }
    }
    return;
  }

  // ---- GEMM path ----
  int t = grp * 2 + r;
  if (t >= GEMM_BLOCKS) return;
  int lane = tid & 63;
  int wv = tid >> 6;
  int node0 = t * 32;
  int fm = lane & 31;
  int fq = lane >> 5;
  int r8 = tid >> 5;   // 0..7
  int c32 = tid & 31;  // 0..31

  const char* xb = (const char*)Xv;
  float4 v0[4], v1[4];
  int rows[4];
#pragma unroll
  for (int i = 0; i < 4; i++) {
    rows[i] = r8 * 4 + i;
    int tk = tokens[min(node0 + rows[i], N_NODES - 1)];
    unsigned off = (unsigned)tk * (D_IN * 4) + (unsigned)c32 * 16;
    v0[i] = *(const float4*)(xb + off);
    v1[i] = *(const float4*)(xb + off + 512);
  }

  f32x16 acc;
#pragma unroll
  for (int q = 0; q < 16; q++) acc[q] = 0.f;

#pragma unroll
  for (int kh = 0; kh < 2; kh++) {
#pragma unroll
    for (int i = 0; i < 4; i++) {
      float4 v = (kh == 0) ? v0[i] : v1[i];
      ushort4 h, l;
      h.x = f2bf(v.x); l.x = f2bf(v.x - bf2f(h.x));
      h.y = f2bf(v.y); l.y = f2bf(v.y - bf2f(h.y));
      h.z = f2bf(v.z); l.z = f2bf(v.z - bf2f(h.z));
      h.w = f2bf(v.w); l.w = f2bf(v.w - bf2f(h.w));
      *(ushort4*)&xh_lds[rows[i] * XS + 4 * c32] = h;
      *(ushort4*)&xl_lds[rows[i] * XS + 4 * c32] = l;
    }
    __syncthreads();

    const ushort_t* wb = Wsw + ((size_t)(wv * 2 + kh) * 8) * 2 * 512 + lane * 8;
#pragma unroll
    for (int tc = 0; tc < 2; tc++) {
      bf16x8 wbh[4], wbl[4];
#pragma unroll
      for (int t4 = 0; t4 < 4; t4++) {
        wbh[t4] = *(const bf16x8*)(wb + (size_t)(tc * 4 + t4) * 1024);
        wbl[t4] = *(const bf16x8*)(wb + (size_t)(tc * 4 + t4) * 1024 + 512);
      }
#pragma unroll
      for (int t4 = 0; t4 < 4; t4++) {
        int ko = (tc * 4 + t4) * 16 + fq * 8;
        bf16x8 ah = *(const bf16x8*)&xh_lds[fm * XS + ko];
        bf16x8 al = *(const bf16x8*)&xl_lds[fm * XS + ko];
        acc = __builtin_amdgcn_mfma_f32_32x32x16_bf16(ah, wbh[t4], acc, 0, 0, 0);
        acc = __builtin_amdgcn_mfma_f32_32x32x16_bf16(ah, wbl[t4], acc, 0, 0, 0);
        acc = __builtin_amdgcn_mfma_f32_32x32x16_bf16(al, wbh[t4], acc, 0, 0, 0);
      }
    }
    if (kh == 0) __syncthreads();  // all reads done before buffer reuse
  }

  int j = wv * 32 + fm;
  float bv = bias[j];
#pragma unroll
  for (int q = 0; q < 16; q++) {
    int row = (q & 3) + 8 * (q >> 2) + 4 * fq;
    int node = node0 + row;
    if (node < N_NODES)
      OutT[(size_t)node * D + j] = f2bf(acc[q] + bv);  // UNSCALED
  }
}

// ---------------- gather primitives ----------------
__device__ __forceinline__ void fma8(float acc[8], uint4 u, float f) {
  acc[0] = fmaf(bflo(u.x), f, acc[0]);
  acc[1] = fmaf(bfhi(u.x), f, acc[1]);
  acc[2] = fmaf(bflo(u.y), f, acc[2]);
  acc[3] = fmaf(bfhi(u.y), f, acc[3]);
  acc[4] = fmaf(bflo(u.z), f, acc[4]);
  acc[5] = fmaf(bfhi(u.z), f, acc[5]);
  acc[6] = fmaf(bflo(u.w), f, acc[6]);
  acc[7] = fmaf(bfhi(u.w), f, acc[7]);
}

__device__ __forceinline__ uint4 ldrow(const char* tbase, int s, int h) {
  return *(const uint4*)(tbase + (((unsigned)s << 8) + ((unsigned)h << 4)));
}

// scaled burst: per-row scale f alongside u (round-10 measured-good form)
__device__ __forceinline__ void burst8s(const char* tbase, int sidx, float scl,
                                        int gbase, int qoff, int h, float acc[8]) {
  uint4 u[8];
  float f[8];
#pragma unroll
  for (int q = 0; q < 8; q++) {
    int s = __shfl(sidx, gbase + qoff + q);
    f[q] = __shfl(scl, gbase + qoff + q);
    u[q] = ldrow(tbase, s, h);
  }
#pragma unroll
  for (int q = 0; q < 8; q++) fma8(acc, u[q], f[q]);
}

// k3/k4 gather: rows UNSCALED, scale by dinv[s]=rsqrt(deg[s]+1) per row.
__device__ __forceinline__ void gather_scaled(
    const char* tbase, const ushort_t* __restrict__ bucket,
    const int* __restrict__ deg, const int* __restrict__ ovf, int novf,
    int node, int degv, bool valid, int gbase, int h, float acc[8]) {
  int cnt = valid ? min(degv, BCAP) : 0;
  int sidx = (h < cnt) ? (int)bucket[node * BCAP + h] : N_NODES;
  float scl = rsqrtf((float)(deg[sidx] + 1));  // deg[N_NODES]=0 -> 1.0, row=0
  burst8s(tbase, sidx, scl, gbase, 0, h, acc);
  burst8s(tbase, sidx, scl, gbase, 8, h, acc);
  for (int b2 = 16; b2 < cnt; b2 += 16) {  // deg in (16,32]: one more batch
    int sx = (b2 + h < cnt) ? (int)bucket[node * BCAP + b2 + h] : N_NODES;
    float sc = rsqrtf((float)(deg[sx] + 1));
    burst8s(tbase, sx, sc, gbase, 0, h, acc);
    burst8s(tbase, sx, sc, gbase, 8, h, acc);
  }
  if (valid && degv > BCAP) {  // exact overflow handling (P~1e-7)
    for (int i = 0; i < novf; i++) {
      if (ovf[2 * i] == node) {
        int s = ovf[2 * i + 1];
        fma8(acc, ldrow(tbase, s, h), rsqrtf((float)(deg[s] + 1)));
      }
    }
  }
}

// epilogue: bias+relu+hi/lo pack -> LDS
__device__ __forceinline__ void epi_lds(
    const float acc[8], bool vv, float di, float4 bA, float4 bB,
    int row, int h, ushort_t* xh_lds, ushort_t* xl_lds) {
  constexpr int XS = 136;
  bf16x8 ph, pl;
  if (vv) {
    float val[8];
    val[0] = fmaxf(di * acc[0] + bA.x, 0.f);
    val[1] = fmaxf(di * acc[1] + bA.y, 0.f);
    val[2] = fmaxf(di * acc[2] + bA.z, 0.f);
    val[3] = fmaxf(di * acc[3] + bA.w, 0.f);
    val[4] = fmaxf(di * acc[4] + bB.x, 0.f);
    val[5] = fmaxf(di * acc[5] + bB.y, 0.f);
    val[6] = fmaxf(di * acc[6] + bB.z, 0.f);
    val[7] = fmaxf(di * acc[7] + bB.w, 0.f);
#pragma unroll
    for (int q = 0; q < 8; q++) {
      ushort_t hq = f2bf(val[q]);
      ph[q] = (short)hq;
      pl[q] = (short)f2bf(val[q] - bf2f(hq));
    }
  } else {
#pragma unroll
    for (int q = 0; q < 8; q++) { ph[q] = 0; pl[q] = 0; }
  }
  *(bf16x8*)&xh_lds[row * XS + h * 8] = ph;
  *(bf16x8*)&xl_lds[row * XS + h * 8] = pl;
}

// ---------------- k3: FUSED aggregate1 + conv2-GEMM ----------------
// Round-10 measured-best structure: both gathers back-to-back (accA/accB
// live together -> both latency chains in flight), epilogues after,
// T2 written UNSCALED (k4 applies per-row dinv).
__global__ __launch_bounds__(256) void k_agg_gemm(
    const ushort_t* __restrict__ t1, const int* __restrict__ deg,
    const ushort_t* __restrict__ bucket, const int* __restrict__ ovfc,
    const int* __restrict__ ovf, const float* __restrict__ b1f,
    const ushort_t* __restrict__ Wsw, ushort_t* __restrict__ OutT2) {
  constexpr int XS = 136;
  __shared__ __align__(16) ushort_t xh_lds[32 * XS];
  __shared__ __align__(16) ushort_t xl_lds[32 * XS];

  int tid = threadIdx.x;
  int lane = tid & 63;
  int wv = tid >> 6;
  int node0 = blockIdx.x * 32;
  int fm = lane & 31;
  int fq = lane >> 5;
  int g = lane >> 4;   // group 0..3
  int h = lane & 15;   // dim-chunk 0..15
  int gbase = lane & 48;

  const char* tb = (const char*)t1;
  float4 bA = *(const float4*)&b1f[h * 8];
  float4 bB = *(const float4*)&b1f[h * 8 + 4];
  int novf = *ovfc;

  // hoisted per-wave deg loads (8 nodes)
  int node0w = node0 + wv * 8;
  int dgl = deg[min(node0w + min(lane, 7), N_NODES - 1)];

  int nodeA = node0w + g;      // pass-0 node (wave rows 0..3)
  int nodeB = node0w + 4 + g;  // pass-1 node (wave rows 4..7)
  int degA = __shfl(dgl, g);
  int degB = __shfl(dgl, 4 + g);
  bool vA = nodeA < N_NODES, vB = nodeB < N_NODES;
  float diA = rsqrtf((float)(degA + 1));
  float diB = rsqrtf((float)(degB + 1));

  float accA[8];
#pragma unroll
  for (int q = 0; q < 8; q++) accA[q] = 0.f;
  fma8(accA, ldrow(tb, vA ? nodeA : N_NODES, h), diA);  // self * own dinv
  gather_scaled(tb, bucket, deg, ovf, novf, nodeA, degA, vA, gbase, h, accA);

  float accB[8];
#pragma unroll
  for (int q = 0; q < 8; q++) accB[q] = 0.f;
  fma8(accB, ldrow(tb, vB ? nodeB : N_NODES, h), diB);
  gather_scaled(tb, bucket, deg, ovf, novf, nodeB, degB, vB, gbase, h, accB);

  // ---- epilogues -> LDS ----
  epi_lds(accA, vA, diA, bA, bB, wv * 8 + g, h, xh_lds, xl_lds);
  epi_lds(accB, vB, diB, bA, bB, wv * 8 + 4 + g, h, xh_lds, xl_lds);
  __syncthreads();

  f32x16 acc;
#pragma unroll
  for (int q = 0; q < 16; q++) acc[q] = 0.f;
  {
    const ushort_t* wb = Wsw + ((size_t)wv * 8) * 2 * 512 + lane * 8;
#pragma unroll
    for (int tc = 0; tc < 2; tc++) {
      bf16x8 wbh[4], wbl[4];
#pragma unroll
      for (int t4 = 0; t4 < 4; t4++) {
        wbh[t4] = *(const bf16x8*)(wb + (size_t)(tc * 4 + t4) * 1024);
        wbl[t4] = *(const bf16x8*)(wb + (size_t)(tc * 4 + t4) * 1024 + 512);
      }
#pragma unroll
      for (int t4 = 0; t4 < 4; t4++) {
        int ko = (tc * 4 + t4) * 16 + fq * 8;
        bf16x8 ah = *(const bf16x8*)&xh_lds[fm * XS + ko];
        bf16x8 al = *(const bf16x8*)&xl_lds[fm * XS + ko];
        acc = __builtin_amdgcn_mfma_f32_32x32x16_bf16(ah, wbh[t4], acc, 0, 0, 0);
        acc = __builtin_amdgcn_mfma_f32_32x32x16_bf16(ah, wbl[t4], acc, 0, 0, 0);
        acc = __builtin_amdgcn_mfma_f32_32x32x16_bf16(al, wbh[t4], acc, 0, 0, 0);
      }
    }
  }
  int j = wv * 32 + fm;
#pragma unroll
  for (int q = 0; q < 16; q++) {
    int row = (q & 3) + 8 * (q >> 2) + 4 * fq;
    int node = node0 + row;
    if (node < N_NODES)
      OutT2[(size_t)node * D + j] = f2bf(acc[q]);  // UNSCALED
  }
}

// ---------------- k4: final aggregation -> fp32 out ----------------
__global__ __launch_bounds__(256) void k_agg_out(
    const ushort_t* __restrict__ t, const int* __restrict__ deg,
    const ushort_t* __restrict__ bucket, const int* __restrict__ ovfc,
    const int* __restrict__ ovf, const float* __restrict__ bias,
    float* __restrict__ out_f) {
  int wv = threadIdx.x >> 6;
  int lane = threadIdx.x & 63;
  int g = lane >> 4;
  int h = lane & 15;
  int gbase = lane & 48;
  int nodew = blockIdx.x * 16 + wv * 4;
  int dgl = deg[min(nodew + min(lane, 3), N_NODES - 1)];
  int node = nodew + g;
  int degn = __shfl(dgl, g);
  bool vn = node < N_NODES;
  float di = rsqrtf((float)(degn + 1));
  int novf = *ovfc;

  const char* tb = (const char*)t;
  float acc[8];
#pragma unroll
  for (int q = 0; q < 8; q++) acc[q] = 0.f;
  fma8(acc, ldrow(tb, vn ? node : N_NODES, h), di);  // self * own dinv
  gather_scaled(tb, bucket, deg, ovf, novf, node, degn, vn, gbase, h, acc);

  if (!vn) return;
  float4 bA = *(const float4*)&bias[h * 8];
  float4 bB = *(const float4*)&bias[h * 8 + 4];
  float4 o0, o1;
  o0.x = di * acc[0] + bA.x;
  o0.y = di * acc[1] + bA.y;
  o0.z = di * acc[2] + bA.z;
  o0.w = di * acc[3] + bA.w;
  o1.x = di * acc[4] + bB.x;
  o1.y = di * acc[5] + bB.y;
  o1.z = di * acc[6] + bB.z;
  o1.w = di * acc[7] + bB.w;
  *(float4*)&out_f[(size_t)node * D + h * 8] = o0;
  *(float4*)&out_f[(size_t)node * D + h * 8 + 4] = o1;
}

extern "C" void kernel_launch(void* const* d_in, const int* in_sizes, int n_in,
                              void* d_out, int out_size, void* d_ws, size_t ws_size,
                              hipStream_t stream) {
  const int* tokens = (const int*)d_in[0];
  const int* edge = (const int*)d_in[1];  // [2][E]
  const float* embed = (const float*)d_in[2];
  const float* Wn = (const float*)d_in[3];
  const float* bn = (const float*)d_in[4];
  const float* w1 = (const float*)d_in[5];
  const float* b1 = (const float*)d_in[6];
  const float* w2 = (const float*)d_in[7];
  const float* b2 = (const float*)d_in[8];
  float* out = (float*)d_out;  // fp32 output

  const int* src = edge;
  const int* dst = edge + N_EDGES;

  char* ws = (char*)d_ws;
  // T1/T2 have one extra ZERO row at index N_NODES (gather padding target)
  ushort_t* T1 = (ushort_t*)ws;                  // 12,800,256 B
  ushort_t* T2 = (ushort_t*)(ws + 12800256);     // 12,800,256 B
  ushort_t* bucket = (ushort_t*)(ws + 25600512); // 3,200,000 B (50K x 32 u16)
  int* deg = (int*)(ws + 28800512);              // 200,064 B (50001 ints, pad)
  int* ovfc = (int*)(ws + 29000576);             // 128 B (isolated counter)
  int* ovf = (int*)(ws + 29000704);              // 16,384 B (2048 pairs)
  ushort_t* WcSw = (ushort_t*)(ws + 29017088);   // 131,072 B (swizzled hi/lo)
  ushort_t* W2Sw = (ushort_t*)(ws + 29148160);   // 65,536 B (swizzled hi/lo)
  float* bias_ws = (float*)(ws + 29213696);      // bc | b1 | b2 (1,536 B)
  float* bcf = bias_ws;
  float* b1f = bias_ws + 128;
  float* b2f = bias_ws + 256;

  // --- k1: weight prep + deg/ovfc zeroing (memset dispatch folded in) ---
  k_wprep<<<194 + ZERO_BLOCKS, 256, 0, stream>>>(
      Wn, w1, bn, w2, b1, b2, WcSw, W2Sw, bias_ws, T1, T2, deg);

  // --- k2: conv1 T1 = gather(e)@Wc^T + bc (UNSCALED) || edge fill ---
  k_gemm_fill<<<MIX_BLOCKS, 256, 0, stream>>>(
      embed, tokens, WcSw, bcf, T1, src, dst, deg, bucket, ovfc, ovf);

  // --- k3: x1 = relu(dinv*agg_scaled(T1)+b1); T2 = x1@w2^T (UNSCALED) ---
  k_agg_gemm<<<GEMM_BLOCKS, 256, 0, stream>>>(
      T1, deg, bucket, ovfc, ovf, b1f, W2Sw, T2);

  // --- k4: out = dinv*agg_scaled(T2) + b2 (fp32) ---
  k_agg_out<<<OUT_CHUNKS, 256, 0, stream>>>(
      T2, deg, bucket, ovfc, ovf, b2f, out);
}